// Round 5
// baseline (443.999 us; speedup 1.0000x reference)
//
#include <hip/hip_runtime.h>

#define LOG2E 1.44269504088896340736f

typedef _Float16 half2_t __attribute__((ext_vector_type(2)));

__device__ __forceinline__ float rlf(float v, int lane) {
    return __int_as_float(__builtin_amdgcn_readlane(__float_as_int(v), lane));
}
__device__ __forceinline__ unsigned rlu(unsigned v, int lane) {
    return (unsigned)__builtin_amdgcn_readlane((int)v, lane);
}
__device__ __forceinline__ unsigned pack2(float a, float b) {
    half2_t v; v.x = (_Float16)a; v.y = (_Float16)b;   // RNE (setup only)
    return __builtin_bit_cast(unsigned, v);
}
__device__ __forceinline__ half2_t ubc(unsigned u) {
    return __builtin_bit_cast(half2_t, u);
}

// Cross-half partner (lane^32) on the VALU pipe (round-9 verified form).
// Kept in the convention-independent xor form deliberately: the cndmask
// form needs to know which of r[0]/r[1] is the partner per half, and a
// wrong guess would destroy this round's measurement.
__device__ __forceinline__ float swap_half(float v) {
#if __has_builtin(__builtin_amdgcn_permlane32_swap)
    const unsigned u = __builtin_bit_cast(unsigned, v);
    auto r = __builtin_amdgcn_permlane32_swap(u, u, false, false);
    return __builtin_bit_cast(float, (unsigned)(r[0] ^ r[1] ^ u));
#else
    return __shfl_xor(v, 32, 64);     // DS fallback (round-5 proven)
#endif
}

// Neighbor (lane^1) via DPP quad_perm [1,0,3,2] — VALU, hazard-handled.
__device__ __forceinline__ float xor1_dpp(float v) {
    return __int_as_float(__builtin_amdgcn_mov_dpp(
        __float_as_int(v), 0xB1, 0xF, 0xF, true));
}

// Round-18: decisive experiment — cadence-bound vs latency-bound.
// R17 (readlane-only broadcast, best: 389.5us, VALUBusy 83, conflicts 0)
// left a model ambiguity: busy==insts*4 fits R13/R15/R17 exactly, which
// either means (a) a single wave issues VALU at most 1/4cyc (cadence model;
// floor = insts*4 = 380cyc) or (b) the counter uses the gfx94x SIMD-16
// formula and real issue is 2cyc/inst (latency model; ~267cyc of stall on
// the carried chain, dominated by the 16-deep fdot2 accumulation chains if
// fdot2 dep-latency ~12cyc). This kernel keeps R17's structure and ONLY:
//  (1) splits each row's dot chain 16-deep -> 4 accumulators of depth 4,
//      operands round-robined in readlane arrival order (R16's regression
//      was its DS-first reorder, not the split); chain inits are free via
//      inline-const acc=0.0f in the first dot of each chain;
//  (2) packs via hpk = pkrtz(dpp(h), h) with readlanes moved to ODD lanes
//      (pair m in lane 2m+1) so LLVM can fold the mov_dpp into pkrtz src0.
// Readout: ~310-330us => latency model (keep splitting/shortening);
// ~405-415us flat-ish => cadence model (next: pure instruction diet).
__global__ __launch_bounds__(64, 1) void lstm_pl_kernel(
    const float* __restrict__ x,      // [B, T]
    const float* __restrict__ W_ih,   // [128]
    const float* __restrict__ W_hh,   // [128, 32]
    const float* __restrict__ b_ih,   // [128]
    const float* __restrict__ b_hh,   // [128]
    const float* __restrict__ W_out,  // [32]
    const float* __restrict__ b_out,  // [1]
    float* __restrict__ out,          // [B, T]
    int T)
{
    __shared__ float psum[64 * 68];   // [step][lane] raw h

    const int b = blockIdx.x;
    const int l = threadIdx.x;        // 0..63
    const int r0 = l;                 // i (l<32) / f (l>=32): sigmoid rows
    const int r1 = l + 64;            // g (l<32) / o (l>=32)
    const bool lo = (l < 32);

    const float sc0 = -LOG2E;                           // sigmoid prescale
    const float sc1 = lo ? (-2.0f * LOG2E) : (-LOG2E);  // tanh / sigmoid

    // Pack prescaled W_hh rows into f16 pairs: 32 resident VGPRs.
    // w0u[m]/w1u[m] multiply h-pair m = (h[2m], h[2m+1]).
    unsigned w0u[16], w1u[16];
#pragma unroll
    for (int m = 0; m < 16; ++m) {
        w0u[m] = pack2(W_hh[r0 * 32 + 2 * m] * sc0,
                       W_hh[r0 * 32 + 2 * m + 1] * sc0);
        w1u[m] = pack2(W_hh[r1 * 32 + 2 * m] * sc1,
                       W_hh[r1 * 32 + 2 * m + 1] * sc1);
    }
#pragma unroll
    for (int m = 0; m < 16; ++m)
        asm volatile("" : "+v"(w0u[m]), "+v"(w1u[m]));  // pin; no remat

    // Epilogue W_out tiles.
    float4 wout4[8];
#pragma unroll
    for (int m = 0; m < 8; ++m)
        wout4[m] = *(const float4*)(W_out + 4 * m);

    const float wih0  = W_ih[r0] * sc0;
    const float wih1  = W_ih[r1] * sc1;
    const float bias0 = (b_ih[r0] + b_hh[r0]) * sc0;
    const float bias1 = (b_ih[r1] + b_hh[r1]) * sc1;
    // s1s: lanes<32 -> -2log2e * tanh(g); lanes>=32 -> sigmoid(o)
    const float A1s = lo ? (-4.0f * LOG2E) : 1.0f;
    const float B1s = lo ? ( 2.0f * LOG2E) : 0.0f;
    const float bout  = b_out[0];

    float h = 0.0f, cs = 0.0f;        // cs = -2*log2e*c  (scaled cell state)
    unsigned hpk = 0u;                // loop-carried packed pair (readlane src)

    const float* xp = x + (size_t)b * T;
    float*       op = out + (size_t)b * T;
    float xv = xp[l];

    for (int t0 = 0; t0 < T; t0 += 64) {
        const int tn = (t0 + 64 < T) ? (t0 + 64) : t0;
        float xv_next = xp[tn + l];   // prefetch next chunk

#pragma unroll 16
        for (int tu = 0; tu < 64; ++tu) {
            const float xt = rlf(xv, tu);

            // Pair m lives in lane 2m+1 of hpk (odd-lane packing, see (2)).
            // Batch 4 readlanes between dot groups: hazard spacing.
            const unsigned q0 = rlu(hpk, 1);
            const unsigned q1 = rlu(hpk, 3);
            const unsigned q2 = rlu(hpk, 5);
            const unsigned q3 = rlu(hpk, 7);

            // 4 accumulator chains per row, depth 4 each; acc = (m & 3).
            float a0 = fmaf(wih0, xt, bias0);
            float a1 = fmaf(wih1, xt, bias1);
            float b0, b1, c0, c1, d0, d1;

#define FD(acc, w, hh)  acc = __builtin_amdgcn_fdot2(ubc(w), ubc(hh), acc, false)
#define FD0(acc, w, hh) acc = __builtin_amdgcn_fdot2(ubc(w), ubc(hh), 0.0f, false)
            FD (a0, w0u[0],  q0);  FD (a1, w1u[0],  q0);
            FD0(b0, w0u[1],  q1);  FD0(b1, w1u[1],  q1);
            const unsigned q4 = rlu(hpk, 9);
            const unsigned q5 = rlu(hpk, 11);
            const unsigned q6 = rlu(hpk, 13);
            const unsigned q7 = rlu(hpk, 15);
            FD0(c0, w0u[2],  q2);  FD0(c1, w1u[2],  q2);
            FD0(d0, w0u[3],  q3);  FD0(d1, w1u[3],  q3);
            const unsigned q8 = rlu(hpk, 17);
            const unsigned q9 = rlu(hpk, 19);
            const unsigned qA = rlu(hpk, 21);
            const unsigned qB = rlu(hpk, 23);
            FD (a0, w0u[4],  q4);  FD (a1, w1u[4],  q4);
            FD (b0, w0u[5],  q5);  FD (b1, w1u[5],  q5);
            const unsigned qC = rlu(hpk, 25);
            const unsigned qD = rlu(hpk, 27);
            const unsigned qE = rlu(hpk, 29);
            const unsigned qF = rlu(hpk, 31);
            FD (c0, w0u[6],  q6);  FD (c1, w1u[6],  q6);
            FD (d0, w0u[7],  q7);  FD (d1, w1u[7],  q7);
            FD (a0, w0u[8],  q8);  FD (a1, w1u[8],  q8);
            FD (b0, w0u[9],  q9);  FD (b1, w1u[9],  q9);
            FD (c0, w0u[10], qA);  FD (c1, w1u[10], qA);
            FD (d0, w0u[11], qB);  FD (d1, w1u[11], qB);
            FD (a0, w0u[12], qC);  FD (a1, w1u[12], qC);
            FD (b0, w0u[13], qD);  FD (b1, w1u[13], qD);
            FD (c0, w0u[14], qE);  FD (c1, w1u[14], qE);
            FD (d0, w0u[15], qF);  FD (d1, w1u[15], qF);
#undef FD
#undef FD0
            const float G0 = (a0 + b0) + (c0 + d0);
            const float G1 = (a1 + b1) + (c1 + d1);

            // s0 = sigmoid(i|f); s1s = -2log2e*tanh(g) (lo) | sigmoid(o)
            const float s0  = __builtin_amdgcn_rcpf(1.0f + __builtin_amdgcn_exp2f(G0));
            const float s1s = fmaf(A1s, __builtin_amdgcn_rcpf(
                                  1.0f + __builtin_amdgcn_exp2f(G1)), B1s);
            const float ig = s0 * s1s;           // i*(-2log2e*g), pre-swap

            // VALU cross-half exchange: lanes<32 get (f, sigmoid(o)).
            const float o0 = swap_half(s0);
            const float o1 = swap_half(s1s);
            const float to1 = o1 + o1;           // off critical path

            // cs = f*cs + i*(-2log2e*g); h = o1*tanh(c) = 2*o1*rcp - o1
            cs = fmaf(o0, cs, ig);
            const float rc = __builtin_amdgcn_rcpf(
                1.0f + __builtin_amdgcn_exp2f(cs));
            h = fmaf(to1, rc, -o1);

            // Pack pair for next step: lane 2m+1 holds (h[2m], h[2m+1]).
            // pkrtz(dpp(h), h): DPP is src0 -> foldable into the cvt.
            const float hn = xor1_dpp(h);
            hpk = __builtin_bit_cast(unsigned,
                      __builtin_amdgcn_cvt_pkrtz(hn, h));
            psum[tu * 68 + l] = h;               // write-only; no wait in loop
        }

        __syncthreads();  // single wave: cheap; drains psum
        // Lane j: out[t0+j] = sum_{k<32} psum[j][k] * W_out[k].
        const float4* row = (const float4*)(psum + l * 68);
        float4 s4;
        {
            float4 v4 = row[0];
            s4.x = v4.x * wout4[0].x; s4.y = v4.y * wout4[0].y;
            s4.z = v4.z * wout4[0].z; s4.w = v4.w * wout4[0].w;
        }
#pragma unroll
        for (int m = 1; m < 8; ++m) {
            float4 v4 = row[m];
            s4.x = fmaf(v4.x, wout4[m].x, s4.x);
            s4.y = fmaf(v4.y, wout4[m].y, s4.y);
            s4.z = fmaf(v4.z, wout4[m].z, s4.z);
            s4.w = fmaf(v4.w, wout4[m].w, s4.w);
        }
        op[t0 + l] = (s4.x + s4.y) + (s4.z + s4.w) + bout;
        __syncthreads();  // next chunk overwrites psum
        xv = xv_next;
    }
}

extern "C" void kernel_launch(void* const* d_in, const int* in_sizes, int n_in,
                              void* d_out, int out_size, void* d_ws, size_t ws_size,
                              hipStream_t stream) {
    const float* x     = (const float*)d_in[0];   // [1024, 2048, 1]
    const float* W_ih  = (const float*)d_in[1];   // [128, 1]
    const float* W_hh  = (const float*)d_in[2];   // [128, 32]
    const float* b_ih  = (const float*)d_in[3];   // [128]
    const float* b_hh  = (const float*)d_in[4];   // [128]
    const float* W_out = (const float*)d_in[5];   // [1, 32]
    const float* b_out = (const float*)d_in[6];   // [1]
    float* out = (float*)d_out;                   // [1024, 2048, 1]

    const int B = 1024;
    const int T = 2048;
    lstm_pl_kernel<<<B, 64, 0, stream>>>(x, W_ih, W_hh, b_ih, b_hh,
                                         W_out, b_out, out, T);
}

// Round 6
// 426.901 us; speedup vs baseline: 1.0400x; 1.0400x over previous
//
#include <hip/hip_runtime.h>

#define LOG2E 1.44269504088896340736f

typedef _Float16 half2_t __attribute__((ext_vector_type(2)));

__device__ __forceinline__ float rlf(float v, int lane) {
    return __int_as_float(__builtin_amdgcn_readlane(__float_as_int(v), lane));
}
__device__ __forceinline__ unsigned rlu(unsigned v, int lane) {
    return (unsigned)__builtin_amdgcn_readlane((int)v, lane);
}
__device__ __forceinline__ unsigned pack2(float a, float b) {
    half2_t v; v.x = (_Float16)a; v.y = (_Float16)b;   // RNE (setup only)
    return __builtin_bit_cast(unsigned, v);
}
__device__ __forceinline__ half2_t ubc(unsigned u) {
    return __builtin_bit_cast(half2_t, u);
}

// Cross-half partner (lane^32) on the VALU pipe (round-9 verified form).
__device__ __forceinline__ float swap_half(float v) {
#if __has_builtin(__builtin_amdgcn_permlane32_swap)
    const unsigned u = __builtin_bit_cast(unsigned, v);
    auto r = __builtin_amdgcn_permlane32_swap(u, u, false, false);
    return __builtin_bit_cast(float, (unsigned)(r[0] ^ r[1] ^ u));
#else
    return __shfl_xor(v, 32, 64);     // DS fallback (round-5 proven)
#endif
}

// Neighbor (lane^1) via DPP quad_perm [1,0,3,2] — VALU, hazard-handled.
__device__ __forceinline__ float xor1_dpp(float v) {
    return __int_as_float(__builtin_amdgcn_mov_dpp(
        __float_as_int(v), 0xB1, 0xF, 0xF, true));
}

// Round-19: cadence model confirmed (R13/R15/R17/R18 all fit
// period = 4cyc * inst_count + ~75cyc serial tail; R18's +7 insts cost
// exactly +27cyc and the depth-4 chain split bought nothing). Single wave
// per SIMD issues ~1 VALU/4cyc, so ONLY instruction count and the tail
// matter. This round: exact R17 revert (best, 389.5us) with ONE change —
// all 16 readlanes hoisted into a single block ahead of the dots. Every
// readlane's consumer then trails it by >=18 issue slots (SGPR-hazard
// cover), and at the unroll seam the scheduler can slide the block into
// the previous step's serial trans tail (~75cyc of idle issue slots),
// hiding most of the readlane issue cost. Single-variable experiment:
// flat result => R17 is within ~15% of the algorithm's cadence floor.
__global__ __launch_bounds__(64, 1) void lstm_pl_kernel(
    const float* __restrict__ x,      // [B, T]
    const float* __restrict__ W_ih,   // [128]
    const float* __restrict__ W_hh,   // [128, 32]
    const float* __restrict__ b_ih,   // [128]
    const float* __restrict__ b_hh,   // [128]
    const float* __restrict__ W_out,  // [32]
    const float* __restrict__ b_out,  // [1]
    float* __restrict__ out,          // [B, T]
    int T)
{
    __shared__ float psum[64 * 68];   // [step][lane] raw h

    const int b = blockIdx.x;
    const int l = threadIdx.x;        // 0..63
    const int r0 = l;                 // i (l<32) / f (l>=32): sigmoid rows
    const int r1 = l + 64;            // g (l<32) / o (l>=32)
    const bool lo = (l < 32);

    const float sc0 = -LOG2E;                           // sigmoid prescale
    const float sc1 = lo ? (-2.0f * LOG2E) : (-LOG2E);  // tanh / sigmoid

    // Pack prescaled W_hh rows into f16 pairs: 32 resident VGPRs.
    // w0u[m]/w1u[m] multiply h-pair m = (h[2m], h[2m+1]).
    unsigned w0u[16], w1u[16];
#pragma unroll
    for (int m = 0; m < 16; ++m) {
        w0u[m] = pack2(W_hh[r0 * 32 + 2 * m] * sc0,
                       W_hh[r0 * 32 + 2 * m + 1] * sc0);
        w1u[m] = pack2(W_hh[r1 * 32 + 2 * m] * sc1,
                       W_hh[r1 * 32 + 2 * m + 1] * sc1);
    }
#pragma unroll
    for (int m = 0; m < 16; ++m)
        asm volatile("" : "+v"(w0u[m]), "+v"(w1u[m]));  // pin; no remat

    // Epilogue W_out tiles.
    float4 wout4[8];
#pragma unroll
    for (int m = 0; m < 8; ++m)
        wout4[m] = *(const float4*)(W_out + 4 * m);

    const float wih0  = W_ih[r0] * sc0;
    const float wih1  = W_ih[r1] * sc1;
    const float bias0 = (b_ih[r0] + b_hh[r0]) * sc0;
    const float bias1 = (b_ih[r1] + b_hh[r1]) * sc1;
    // s1s: lanes<32 -> -2log2e * tanh(g); lanes>=32 -> sigmoid(o)
    const float A1s = lo ? (-4.0f * LOG2E) : 1.0f;
    const float B1s = lo ? ( 2.0f * LOG2E) : 0.0f;
    const float bout  = b_out[0];

    float h = 0.0f, cs = 0.0f;        // cs = -2*log2e*c  (scaled cell state)
    unsigned hpk = 0u;                // loop-carried packed pair (readlane src)

    const float* xp = x + (size_t)b * T;
    float*       op = out + (size_t)b * T;
    float xv = xp[l];

    for (int t0 = 0; t0 < T; t0 += 64) {
        const int tn = (t0 + 64 < T) ? (t0 + 64) : t0;
        float xv_next = xp[tn + l];   // prefetch next chunk

#pragma unroll 16
        for (int tu = 0; tu < 64; ++tu) {
            const float xt = rlf(xv, tu);

            // Pair m lives in lane 2m of hpk. ALL 16 readlanes up front:
            // consumers trail by >=18 slots (hazard cover), and the whole
            // block can slide into the previous step's serial tail.
            const unsigned q0 = rlu(hpk, 0);
            const unsigned q1 = rlu(hpk, 2);
            const unsigned q2 = rlu(hpk, 4);
            const unsigned q3 = rlu(hpk, 6);
            const unsigned q4 = rlu(hpk, 8);
            const unsigned q5 = rlu(hpk, 10);
            const unsigned q6 = rlu(hpk, 12);
            const unsigned q7 = rlu(hpk, 14);
            const unsigned q8 = rlu(hpk, 16);
            const unsigned q9 = rlu(hpk, 18);
            const unsigned qA = rlu(hpk, 20);
            const unsigned qB = rlu(hpk, 22);
            const unsigned qC = rlu(hpk, 24);
            const unsigned qD = rlu(hpk, 26);
            const unsigned qE = rlu(hpk, 28);
            const unsigned qF = rlu(hpk, 30);

            float a0 = fmaf(wih0, xt, bias0);
            float a1 = fmaf(wih1, xt, bias1);
            float b0 = 0.0f, b1 = 0.0f;

#define FD(acc, w, hh) acc = __builtin_amdgcn_fdot2(ubc(w), ubc(hh), acc, false)
            FD(a0, w0u[0],  q0);  FD(b0, w0u[1],  q1);
            FD(a1, w1u[0],  q0);  FD(b1, w1u[1],  q1);
            FD(a0, w0u[2],  q2);  FD(b0, w0u[3],  q3);
            FD(a1, w1u[2],  q2);  FD(b1, w1u[3],  q3);
            FD(a0, w0u[4],  q4);  FD(b0, w0u[5],  q5);
            FD(a1, w1u[4],  q4);  FD(b1, w1u[5],  q5);
            FD(a0, w0u[6],  q6);  FD(b0, w0u[7],  q7);
            FD(a1, w1u[6],  q6);  FD(b1, w1u[7],  q7);
            FD(a0, w0u[8],  q8);  FD(b0, w0u[9],  q9);
            FD(a1, w1u[8],  q8);  FD(b1, w1u[9],  q9);
            FD(a0, w0u[10], qA);  FD(b0, w0u[11], qB);
            FD(a1, w1u[10], qA);  FD(b1, w1u[11], qB);
            FD(a0, w0u[12], qC);  FD(b0, w0u[13], qD);
            FD(a1, w1u[12], qC);  FD(b1, w1u[13], qD);
            FD(a0, w0u[14], qE);  FD(b0, w0u[15], qF);
            FD(a1, w1u[14], qE);  FD(b1, w1u[15], qF);
#undef FD
            const float G0 = a0 + b0;
            const float G1 = a1 + b1;

            // s0 = sigmoid(i|f); s1s = -2log2e*tanh(g) (lo) | sigmoid(o)
            const float s0  = __builtin_amdgcn_rcpf(1.0f + __builtin_amdgcn_exp2f(G0));
            const float s1s = fmaf(A1s, __builtin_amdgcn_rcpf(
                                  1.0f + __builtin_amdgcn_exp2f(G1)), B1s);
            const float ig = s0 * s1s;           // i*(-2log2e*g), pre-swap

            // VALU cross-half exchange: lanes<32 get (f, sigmoid(o)).
            const float o0 = swap_half(s0);
            const float o1 = swap_half(s1s);
            const float to1 = o1 + o1;           // off critical path

            // cs = f*cs + i*(-2log2e*g); h = o1*tanh(c) = 2*o1*rcp - o1
            cs = fmaf(o0, cs, ig);
            const float rc = __builtin_amdgcn_rcpf(
                1.0f + __builtin_amdgcn_exp2f(cs));
            h = fmaf(to1, rc, -o1);

            // Pack pair for next step's readlanes; store raw h for epilogue.
            const float hn = xor1_dpp(h);
            hpk = __builtin_bit_cast(unsigned,
                      __builtin_amdgcn_cvt_pkrtz(h, hn));
            psum[tu * 68 + l] = h;               // write-only; no wait in loop
        }

        __syncthreads();  // single wave: cheap; drains psum
        // Lane j: out[t0+j] = sum_{k<32} psum[j][k] * W_out[k].
        const float4* row = (const float4*)(psum + l * 68);
        float4 s4;
        {
            float4 v4 = row[0];
            s4.x = v4.x * wout4[0].x; s4.y = v4.y * wout4[0].y;
            s4.z = v4.z * wout4[0].z; s4.w = v4.w * wout4[0].w;
        }
#pragma unroll
        for (int m = 1; m < 8; ++m) {
            float4 v4 = row[m];
            s4.x = fmaf(v4.x, wout4[m].x, s4.x);
            s4.y = fmaf(v4.y, wout4[m].y, s4.y);
            s4.z = fmaf(v4.z, wout4[m].z, s4.z);
            s4.w = fmaf(v4.w, wout4[m].w, s4.w);
        }
        op[t0 + l] = (s4.x + s4.y) + (s4.z + s4.w) + bout;
        __syncthreads();  // next chunk overwrites psum
        xv = xv_next;
    }
}

extern "C" void kernel_launch(void* const* d_in, const int* in_sizes, int n_in,
                              void* d_out, int out_size, void* d_ws, size_t ws_size,
                              hipStream_t stream) {
    const float* x     = (const float*)d_in[0];   // [1024, 2048, 1]
    const float* W_ih  = (const float*)d_in[1];   // [128, 1]
    const float* W_hh  = (const float*)d_in[2];   // [128, 32]
    const float* b_ih  = (const float*)d_in[3];   // [128]
    const float* b_hh  = (const float*)d_in[4];   // [128]
    const float* W_out = (const float*)d_in[5];   // [1, 32]
    const float* b_out = (const float*)d_in[6];   // [1]
    float* out = (float*)d_out;                   // [1024, 2048, 1]

    const int B = 1024;
    const int T = 2048;
    lstm_pl_kernel<<<B, 64, 0, stream>>>(x, W_ih, W_hh, b_ih, b_hh,
                                         W_out, b_out, out, T);
}

// Round 7
// 388.690 us; speedup vs baseline: 1.1423x; 1.0983x over previous
//
#include <hip/hip_runtime.h>

#define LOG2E 1.44269504088896340736f

typedef _Float16 half2_t __attribute__((ext_vector_type(2)));

__device__ __forceinline__ float rlf(float v, int lane) {
    return __int_as_float(__builtin_amdgcn_readlane(__float_as_int(v), lane));
}
__device__ __forceinline__ unsigned rlu(unsigned v, int lane) {
    return (unsigned)__builtin_amdgcn_readlane((int)v, lane);
}
__device__ __forceinline__ unsigned pack2(float a, float b) {
    half2_t v; v.x = (_Float16)a; v.y = (_Float16)b;   // RNE (setup only)
    return __builtin_bit_cast(unsigned, v);
}
__device__ __forceinline__ half2_t ubc(unsigned u) {
    return __builtin_bit_cast(half2_t, u);
}

// Cross-half partner (lane^32) on the VALU pipe (round-9 verified xor form —
// convention-independent, keep).
__device__ __forceinline__ float swap_half(float v) {
#if __has_builtin(__builtin_amdgcn_permlane32_swap)
    const unsigned u = __builtin_bit_cast(unsigned, v);
    auto r = __builtin_amdgcn_permlane32_swap(u, u, false, false);
    return __builtin_bit_cast(float, (unsigned)(r[0] ^ r[1] ^ u));
#else
    return __shfl_xor(v, 32, 64);     // DS fallback (round-5 proven)
#endif
}

// Neighbor (lane^1) via DPP quad_perm [1,0,3,2] — VALU, hazard-handled.
__device__ __forceinline__ float xor1_dpp(float v) {
    return __int_as_float(__builtin_amdgcn_mov_dpp(
        __float_as_int(v), 0xB1, 0xF, 0xF, true));
}

// Round-20: upper-half cell update. Cadence model (locked by R18/R19):
// period = 4cyc*insts + exposed tail latency (~77cyc = the serial chain
// G->exp2->rcp->swap->cs->exp2->rcp->h->pack with no parallel work).
// Change vs R17 (best, 389.5us):
//  (1) The cell state lives in lanes>=32, where sigma(f) (row 32+k) and
//      sigma(o) (row 96+k) are computed NATIVELY. Lower lanes compute only
//      ig = sigma(i)*(-2log2e*tanh(g)) (i,g native there) and ONE swap
//      sends ig up. This deletes one swap_half entirely (-3 insts) and
//      takes the swap OFF the critical chain (ig-swap overlaps the upper
//      half's sigma(f) trans chain). h, pack, publish all happen in upper
//      lanes; readlanes source lanes 32+2m; psum cols remapped by a
//      precomputed per-lane address (lower lanes park in cols 36..67,
//      never read by the epilogue; lower-lane cs garbage never consumed).
//  (2) Single accumulator chain per row (a0/a1 interleaved, dep spacing
//      8cyc; R18 proved chain depth free): -2 merge adds.
// Everything else identical to R17. Predict ~430cyc/step => ~365us.
__global__ __launch_bounds__(64, 1) void lstm_pl_kernel(
    const float* __restrict__ x,      // [B, T]
    const float* __restrict__ W_ih,   // [128]
    const float* __restrict__ W_hh,   // [128, 32]
    const float* __restrict__ b_ih,   // [128]
    const float* __restrict__ b_hh,   // [128]
    const float* __restrict__ W_out,  // [32]
    const float* __restrict__ b_out,  // [1]
    float* __restrict__ out,          // [B, T]
    int T)
{
    __shared__ float psum[64 * 68];   // [step][col]; cols 0..31 = h, 36..67 park

    const int b = blockIdx.x;
    const int l = threadIdx.x;        // 0..63
    const int r0 = l;                 // i (l<32) / f (l>=32): sigmoid rows
    const int r1 = l + 64;            // g (l<32) / o (l>=32)
    const bool lo = (l < 32);

    const float sc0 = -LOG2E;                           // sigmoid prescale
    const float sc1 = lo ? (-2.0f * LOG2E) : (-LOG2E);  // tanh / sigmoid

    // Pack prescaled W_hh rows into f16 pairs: 32 resident VGPRs.
    // w0u[m]/w1u[m] multiply h-pair m = (h[2m], h[2m+1]).
    unsigned w0u[16], w1u[16];
#pragma unroll
    for (int m = 0; m < 16; ++m) {
        w0u[m] = pack2(W_hh[r0 * 32 + 2 * m] * sc0,
                       W_hh[r0 * 32 + 2 * m + 1] * sc0);
        w1u[m] = pack2(W_hh[r1 * 32 + 2 * m] * sc1,
                       W_hh[r1 * 32 + 2 * m + 1] * sc1);
    }
#pragma unroll
    for (int m = 0; m < 16; ++m)
        asm volatile("" : "+v"(w0u[m]), "+v"(w1u[m]));  // pin; no remat

    // Epilogue W_out tiles.
    float4 wout4[8];
#pragma unroll
    for (int m = 0; m < 8; ++m)
        wout4[m] = *(const float4*)(W_out + 4 * m);

    const float wih0  = W_ih[r0] * sc0;
    const float wih1  = W_ih[r1] * sc1;
    const float bias0 = (b_ih[r0] + b_hh[r0]) * sc0;
    const float bias1 = (b_ih[r1] + b_hh[r1]) * sc1;
    // s1s: lanes<32 -> -2log2e * tanh(g); lanes>=32 -> sigmoid(o)
    const float A1s = lo ? (-4.0f * LOG2E) : 1.0f;
    const float B1s = lo ? ( 2.0f * LOG2E) : 0.0f;
    const float bout  = b_out[0];

    // psum column: upper lane 32+k owns unit k -> col k; lower lanes park.
    const int pcol = lo ? (36 + l) : (l - 32);

    float h = 0.0f, cs = 0.0f;        // cs = -2*log2e*c, VALID IN UPPER lanes
    unsigned hpk = 0u;                // packed pair, valid in upper lanes

    const float* xp = x + (size_t)b * T;
    float*       op = out + (size_t)b * T;
    float xv = xp[l];

    for (int t0 = 0; t0 < T; t0 += 64) {
        const int tn = (t0 + 64 < T) ? (t0 + 64) : t0;
        float xv_next = xp[tn + l];   // prefetch next chunk

#pragma unroll 16
        for (int tu = 0; tu < 64; ++tu) {
            const float xt = rlf(xv, tu);

            // Pair m lives in UPPER lane 32+2m of hpk. Batches of 4
            // readlanes between dot groups (R17 placement, proven).
            const unsigned q0 = rlu(hpk, 32);
            const unsigned q1 = rlu(hpk, 34);
            const unsigned q2 = rlu(hpk, 36);
            const unsigned q3 = rlu(hpk, 38);

            // Single accumulator chain per row; a0/a1 interleaved so each
            // chain's dep spacing is 2 insts (8cyc) — latency-safe.
            float a0 = fmaf(wih0, xt, bias0);
            float a1 = fmaf(wih1, xt, bias1);

#define FD(acc, w, hh) acc = __builtin_amdgcn_fdot2(ubc(w), ubc(hh), acc, false)
            FD(a0, w0u[0],  q0);  FD(a1, w1u[0],  q0);
            FD(a0, w0u[1],  q1);  FD(a1, w1u[1],  q1);
            const unsigned q4 = rlu(hpk, 40);
            const unsigned q5 = rlu(hpk, 42);
            const unsigned q6 = rlu(hpk, 44);
            const unsigned q7 = rlu(hpk, 46);
            FD(a0, w0u[2],  q2);  FD(a1, w1u[2],  q2);
            FD(a0, w0u[3],  q3);  FD(a1, w1u[3],  q3);
            const unsigned q8 = rlu(hpk, 48);
            const unsigned q9 = rlu(hpk, 50);
            const unsigned qA = rlu(hpk, 52);
            const unsigned qB = rlu(hpk, 54);
            FD(a0, w0u[4],  q4);  FD(a1, w1u[4],  q4);
            FD(a0, w0u[5],  q5);  FD(a1, w1u[5],  q5);
            const unsigned qC = rlu(hpk, 56);
            const unsigned qD = rlu(hpk, 58);
            const unsigned qE = rlu(hpk, 60);
            const unsigned qF = rlu(hpk, 62);
            FD(a0, w0u[6],  q6);  FD(a1, w1u[6],  q6);
            FD(a0, w0u[7],  q7);  FD(a1, w1u[7],  q7);
            FD(a0, w0u[8],  q8);  FD(a1, w1u[8],  q8);
            FD(a0, w0u[9],  q9);  FD(a1, w1u[9],  q9);
            FD(a0, w0u[10], qA);  FD(a1, w1u[10], qA);
            FD(a0, w0u[11], qB);  FD(a1, w1u[11], qB);
            FD(a0, w0u[12], qC);  FD(a1, w1u[12], qC);
            FD(a0, w0u[13], qD);  FD(a1, w1u[13], qD);
            FD(a0, w0u[14], qE);  FD(a1, w1u[14], qE);
            FD(a0, w0u[15], qF);  FD(a1, w1u[15], qF);
#undef FD

            // s0:  lower sigma(i) | upper sigma(f)   (both native rows)
            // s1s: lower -2log2e*tanh(g) | upper sigma(o)
            const float s0  = __builtin_amdgcn_rcpf(1.0f + __builtin_amdgcn_exp2f(a0));
            const float s1s = fmaf(A1s, __builtin_amdgcn_rcpf(
                                  1.0f + __builtin_amdgcn_exp2f(a1)), B1s);

            // Lower computes ig; ONE swap sends it up (overlaps upper's
            // sigma(f) trans chain — off the critical path).
            const float ig  = s0 * s1s;          // valid in lower
            const float igx = swap_half(ig);     // upper receives ig

            // Upper-half cell update with native sigma(f), sigma(o):
            // cs = f*cs + ig; h = sigma(o)*tanh(c) = 2*sigma(o)*rc - sigma(o)
            cs = fmaf(s0, cs, igx);              // valid in upper
            const float rc = __builtin_amdgcn_rcpf(
                1.0f + __builtin_amdgcn_exp2f(cs));
            const float ts = s1s + s1s;          // off critical path
            h = fmaf(ts, rc, -s1s);              // valid in upper

            // Pack pair in upper lanes; publish raw h for the epilogue.
            const float hn = xor1_dpp(h);
            hpk = __builtin_bit_cast(unsigned,
                      __builtin_amdgcn_cvt_pkrtz(h, hn));
            psum[tu * 68 + pcol] = h;            // write-only; no wait in loop
        }

        __syncthreads();  // single wave: cheap; drains psum
        // Lane j: out[t0+j] = sum_{k<32} psum[j][k] * W_out[k].
        const float4* row = (const float4*)(psum + l * 68);
        float4 s4;
        {
            float4 v4 = row[0];
            s4.x = v4.x * wout4[0].x; s4.y = v4.y * wout4[0].y;
            s4.z = v4.z * wout4[0].z; s4.w = v4.w * wout4[0].w;
        }
#pragma unroll
        for (int m = 1; m < 8; ++m) {
            float4 v4 = row[m];
            s4.x = fmaf(v4.x, wout4[m].x, s4.x);
            s4.y = fmaf(v4.y, wout4[m].y, s4.y);
            s4.z = fmaf(v4.z, wout4[m].z, s4.z);
            s4.w = fmaf(v4.w, wout4[m].w, s4.w);
        }
        op[t0 + l] = (s4.x + s4.y) + (s4.z + s4.w) + bout;
        __syncthreads();  // next chunk overwrites psum
        xv = xv_next;
    }
}

extern "C" void kernel_launch(void* const* d_in, const int* in_sizes, int n_in,
                              void* d_out, int out_size, void* d_ws, size_t ws_size,
                              hipStream_t stream) {
    const float* x     = (const float*)d_in[0];   // [1024, 2048, 1]
    const float* W_ih  = (const float*)d_in[1];   // [128, 1]
    const float* W_hh  = (const float*)d_in[2];   // [128, 32]
    const float* b_ih  = (const float*)d_in[3];   // [128]
    const float* b_hh  = (const float*)d_in[4];   // [128]
    const float* W_out = (const float*)d_in[5];   // [1, 32]
    const float* b_out = (const float*)d_in[6];   // [1]
    float* out = (float*)d_out;                   // [1024, 2048, 1]

    const int B = 1024;
    const int T = 2048;
    lstm_pl_kernel<<<B, 64, 0, stream>>>(x, W_ih, W_hh, b_ih, b_hh,
                                         W_out, b_out, out, T);
}

// Round 8
// 369.940 us; speedup vs baseline: 1.2002x; 1.0507x over previous
//
#include <hip/hip_runtime.h>

#define LOG2E 1.44269504088896340736f

typedef _Float16 half2_t __attribute__((ext_vector_type(2)));

__device__ __forceinline__ float rlf(float v, int lane) {
    return __int_as_float(__builtin_amdgcn_readlane(__float_as_int(v), lane));
}
__device__ __forceinline__ unsigned rlu(unsigned v, int lane) {
    return (unsigned)__builtin_amdgcn_readlane((int)v, lane);
}
__device__ __forceinline__ unsigned pack2(float a, float b) {
    half2_t v; v.x = (_Float16)a; v.y = (_Float16)b;   // RNE (setup only)
    return __builtin_bit_cast(unsigned, v);
}
__device__ __forceinline__ half2_t ubc(unsigned u) {
    return __builtin_bit_cast(half2_t, u);
}

// Neighbor (lane^1) via DPP quad_perm [1,0,3,2] — VALU, hazard-handled,
// convention proven in-kernel since round 13.
__device__ __forceinline__ float xor1_dpp(float v) {
    return __int_as_float(__builtin_amdgcn_mov_dpp(
        __float_as_int(v), 0xB1, 0xF, 0xF, true));
}
// lane^2 via quad_perm [2,3,0,1] — fetches the other odd lane of the quad.
__device__ __forceinline__ float xor2_dpp(float v) {
    return __int_as_float(__builtin_amdgcn_mov_dpp(
        __float_as_int(v), 0x4E, 0xF, 0xF, true));
}

// Round-21: adjacent-lane unit mapping — the cross-lane transfer drops from
// lane^32 (permlane32_swap + 2 convention-guard xors, 3 insts / 3 levels)
// to lane^1 (ONE quad_perm DPP). Unit k owns lanes (2k, 2k+1):
//   even lane 2k:  rows (k, 64+k)  = (i_k, g_k) -> computes ig
//   odd  lane 2k+1: rows (32+k, 96+k) = (f_k, o_k) -> owns cell state, h
// ig travels even->odd via xor1_dpp (known-good 0xB1). The pack pair
// (h_2m, h_2m+1) is formed in lane 4m+1 from its own h and lane 4m+3's h
// (same quad: one 0x4E quad_perm). Readlanes source lanes 4m+1. This is
// R20 with the swap replaced; everything else identical (cadence model:
// period = 4cyc*insts + exposed tail; -2 insts, -2 tail levels).
__global__ __launch_bounds__(64, 1) void lstm_pl_kernel(
    const float* __restrict__ x,      // [B, T]
    const float* __restrict__ W_ih,   // [128]
    const float* __restrict__ W_hh,   // [128, 32]
    const float* __restrict__ b_ih,   // [128]
    const float* __restrict__ b_hh,   // [128]
    const float* __restrict__ W_out,  // [32]
    const float* __restrict__ b_out,  // [1]
    float* __restrict__ out,          // [B, T]
    int T)
{
    __shared__ float psum[64 * 68];   // [step][col]; cols 0..31 = h, 36..67 park

    const int b = blockIdx.x;
    const int l = threadIdx.x;        // 0..63
    const int k = l >> 1;             // unit index
    const bool ev = !(l & 1);         // even: (i,g) producer; odd: (f,o)+cell

    const int r0 = ev ? k        : 32 + k;   // i | f  (sigmoid rows)
    const int r1 = ev ? 64 + k   : 96 + k;   // g | o

    const float sc0 = -LOG2E;                            // sigmoid prescale
    const float sc1 = ev ? (-2.0f * LOG2E) : (-LOG2E);   // tanh | sigmoid

    // Pack prescaled W_hh rows into f16 pairs: 32 resident VGPRs.
    // w0u[m]/w1u[m] multiply h-pair m = (h[2m], h[2m+1]).
    unsigned w0u[16], w1u[16];
#pragma unroll
    for (int m = 0; m < 16; ++m) {
        w0u[m] = pack2(W_hh[r0 * 32 + 2 * m] * sc0,
                       W_hh[r0 * 32 + 2 * m + 1] * sc0);
        w1u[m] = pack2(W_hh[r1 * 32 + 2 * m] * sc1,
                       W_hh[r1 * 32 + 2 * m + 1] * sc1);
    }
#pragma unroll
    for (int m = 0; m < 16; ++m)
        asm volatile("" : "+v"(w0u[m]), "+v"(w1u[m]));  // pin; no remat

    // Epilogue W_out tiles.
    float4 wout4[8];
#pragma unroll
    for (int m = 0; m < 8; ++m)
        wout4[m] = *(const float4*)(W_out + 4 * m);

    const float wih0  = W_ih[r0] * sc0;
    const float wih1  = W_ih[r1] * sc1;
    const float bias0 = (b_ih[r0] + b_hh[r0]) * sc0;
    const float bias1 = (b_ih[r1] + b_hh[r1]) * sc1;
    // s1s: even -> -2log2e * tanh(g); odd -> sigmoid(o)
    const float A1s = ev ? (-4.0f * LOG2E) : 1.0f;
    const float B1s = ev ? ( 2.0f * LOG2E) : 0.0f;
    const float bout  = b_out[0];

    // psum column: odd lane 2k+1 owns unit k -> col k; even lanes park.
    const int pcol = ev ? (36 + k) : k;

    float h = 0.0f, cs = 0.0f;        // cs = -2*log2e*c, VALID IN ODD lanes
    unsigned hpk = 0u;                // packed pair, valid in lanes 4m+1

    const float* xp = x + (size_t)b * T;
    float*       op = out + (size_t)b * T;
    float xv = xp[l];

    for (int t0 = 0; t0 < T; t0 += 64) {
        const int tn = (t0 + 64 < T) ? (t0 + 64) : t0;
        float xv_next = xp[tn + l];   // prefetch next chunk

#pragma unroll 16
        for (int tu = 0; tu < 64; ++tu) {
            const float xt = rlf(xv, tu);

            // Pair m lives in lane 4m+1 of hpk. Batches of 4 readlanes
            // between dot groups (R17 placement, proven).
            const unsigned q0 = rlu(hpk, 1);
            const unsigned q1 = rlu(hpk, 5);
            const unsigned q2 = rlu(hpk, 9);
            const unsigned q3 = rlu(hpk, 13);

            // Single accumulator chain per row; a0/a1 interleaved so each
            // chain's dep spacing is 2 insts — latency-safe (R18 proven).
            float a0 = fmaf(wih0, xt, bias0);
            float a1 = fmaf(wih1, xt, bias1);

#define FD(acc, w, hh) acc = __builtin_amdgcn_fdot2(ubc(w), ubc(hh), acc, false)
            FD(a0, w0u[0],  q0);  FD(a1, w1u[0],  q0);
            FD(a0, w0u[1],  q1);  FD(a1, w1u[1],  q1);
            const unsigned q4 = rlu(hpk, 17);
            const unsigned q5 = rlu(hpk, 21);
            const unsigned q6 = rlu(hpk, 25);
            const unsigned q7 = rlu(hpk, 29);
            FD(a0, w0u[2],  q2);  FD(a1, w1u[2],  q2);
            FD(a0, w0u[3],  q3);  FD(a1, w1u[3],  q3);
            const unsigned q8 = rlu(hpk, 33);
            const unsigned q9 = rlu(hpk, 37);
            const unsigned qA = rlu(hpk, 41);
            const unsigned qB = rlu(hpk, 45);
            FD(a0, w0u[4],  q4);  FD(a1, w1u[4],  q4);
            FD(a0, w0u[5],  q5);  FD(a1, w1u[5],  q5);
            const unsigned qC = rlu(hpk, 49);
            const unsigned qD = rlu(hpk, 53);
            const unsigned qE = rlu(hpk, 57);
            const unsigned qF = rlu(hpk, 61);
            FD(a0, w0u[6],  q6);  FD(a1, w1u[6],  q6);
            FD(a0, w0u[7],  q7);  FD(a1, w1u[7],  q7);
            FD(a0, w0u[8],  q8);  FD(a1, w1u[8],  q8);
            FD(a0, w0u[9],  q9);  FD(a1, w1u[9],  q9);
            FD(a0, w0u[10], qA);  FD(a1, w1u[10], qA);
            FD(a0, w0u[11], qB);  FD(a1, w1u[11], qB);
            FD(a0, w0u[12], qC);  FD(a1, w1u[12], qC);
            FD(a0, w0u[13], qD);  FD(a1, w1u[13], qD);
            FD(a0, w0u[14], qE);  FD(a1, w1u[14], qE);
            FD(a0, w0u[15], qF);  FD(a1, w1u[15], qF);
#undef FD

            // s0:  even sigma(i) | odd sigma(f)   (native rows)
            // s1s: even -2log2e*tanh(g) | odd sigma(o)
            const float s0  = __builtin_amdgcn_rcpf(1.0f + __builtin_amdgcn_exp2f(a0));
            const float s1s = fmaf(A1s, __builtin_amdgcn_rcpf(
                                  1.0f + __builtin_amdgcn_exp2f(a1)), B1s);

            // Even computes ig; ONE lane^1 DPP sends it to the odd lane.
            const float ig  = s0 * s1s;          // valid in even
            const float igx = xor1_dpp(ig);      // odd receives ig
                                                 // (even gets odd garbage,
                                                 //  bounded, never NaN)

            // Odd-lane cell update with native sigma(f), sigma(o):
            // cs = f*cs + ig; h = sigma(o)*tanh(c) = 2*sigma(o)*rc - sigma(o)
            cs = fmaf(s0, cs, igx);              // valid in odd
            const float rc = __builtin_amdgcn_rcpf(
                1.0f + __builtin_amdgcn_exp2f(cs));
            const float ts = s1s + s1s;          // off critical path
            h = fmaf(ts, rc, -s1s);              // valid in odd

            // Pack pair in lane 4m+1: own h (unit 2m) + lane 4m+3's h
            // (unit 2m+1) via in-quad lane^2 fetch.
            const float hn = xor2_dpp(h);
            hpk = __builtin_bit_cast(unsigned,
                      __builtin_amdgcn_cvt_pkrtz(h, hn));
            psum[tu * 68 + pcol] = h;            // write-only; no wait in loop
        }

        __syncthreads();  // single wave: cheap; drains psum
        // Lane j: out[t0+j] = sum_{k<32} psum[j][k] * W_out[k].
        const float4* row = (const float4*)(psum + l * 68);
        float4 s4;
        {
            float4 v4 = row[0];
            s4.x = v4.x * wout4[0].x; s4.y = v4.y * wout4[0].y;
            s4.z = v4.z * wout4[0].z; s4.w = v4.w * wout4[0].w;
        }
#pragma unroll
        for (int m = 1; m < 8; ++m) {
            float4 v4 = row[m];
            s4.x = fmaf(v4.x, wout4[m].x, s4.x);
            s4.y = fmaf(v4.y, wout4[m].y, s4.y);
            s4.z = fmaf(v4.z, wout4[m].z, s4.z);
            s4.w = fmaf(v4.w, wout4[m].w, s4.w);
        }
        op[t0 + l] = (s4.x + s4.y) + (s4.z + s4.w) + bout;
        __syncthreads();  // next chunk overwrites psum
        xv = xv_next;
    }
}

extern "C" void kernel_launch(void* const* d_in, const int* in_sizes, int n_in,
                              void* d_out, int out_size, void* d_ws, size_t ws_size,
                              hipStream_t stream) {
    const float* x     = (const float*)d_in[0];   // [1024, 2048, 1]
    const float* W_ih  = (const float*)d_in[1];   // [128, 1]
    const float* W_hh  = (const float*)d_in[2];   // [128, 32]
    const float* b_ih  = (const float*)d_in[3];   // [128]
    const float* b_hh  = (const float*)d_in[4];   // [128]
    const float* W_out = (const float*)d_in[5];   // [1, 32]
    const float* b_out = (const float*)d_in[6];   // [1]
    float* out = (float*)d_out;                   // [1024, 2048, 1]

    const int B = 1024;
    const int T = 2048;
    lstm_pl_kernel<<<B, 64, 0, stream>>>(x, W_ih, W_hh, b_ih, b_hh,
                                         W_out, b_out, out, T);
}